// Round 15
// baseline (466.896 us; speedup 1.0000x reference)
//
#include <hip/hip_runtime.h>
#include <math.h>

#define BB 64
#define TT 512
#define OBSD 115
#define DMD 128
#define DSD 8
#define NLD 3
#define EMBD 16
#define NAD 19
#define H1D 256
#define NTOK (BB*TT)
#define SSEG 32
#define TSEG (TT/SSEG)   // 16

typedef unsigned short ushort_t;
typedef __attribute__((ext_vector_type(8))) short short8;
typedef __attribute__((ext_vector_type(4))) float f32x4;

__device__ __forceinline__ float silu_f(float x){ return x / (1.f + __expf(-x)); }
__device__ __forceinline__ float softplus_f(float x){
  return fmaxf(x, 0.f) + log1pf(__expf(-fabsf(x)));
}
__device__ __forceinline__ ushort_t f2bf(float x){
  unsigned u = __float_as_uint(x);
  unsigned r = (u + 0x7fffu + ((u >> 16) & 1u)) >> 16;
  return (ushort_t)r;
}
__device__ __forceinline__ float b2f(ushort_t x){
  return __uint_as_float(((unsigned)x) << 16);
}
#define MFMA(a,b,c) __builtin_amdgcn_mfma_f32_16x16x32_bf16((a),(b),(c),0,0,0)
#define LOG2E 1.44269504f

// LN stats over 32 tokens, D cols, stride SV floats (SV%32==8 -> conflict-free).
template<int D, int SV>
__device__ __forceinline__ void ln32(const float* s_val, float* s_mr, int tid){
  const int t = tid >> 3, part = tid & 7;
  float s = 0.f, s2 = 0.f;
  #pragma unroll
  for (int j = part; j < D; j += 8){ float v = s_val[t*SV + j]; s += v; s2 = fmaf(v, v, s2); }
  s += __shfl_xor(s, 1, 64); s2 += __shfl_xor(s2, 1, 64);
  s += __shfl_xor(s, 2, 64); s2 += __shfl_xor(s2, 2, 64);
  s += __shfl_xor(s, 4, 64); s2 += __shfl_xor(s2, 4, 64);
  if (part == 0){
    float m = s * (1.f/(float)D);
    s_mr[t*2] = m;
    s_mr[t*2+1] = rsqrtf(s2 * (1.f/(float)D) - m*m + 1e-5f);
  }
}

// ---------------- k_prep ----------------
struct PJob { const float* src; ushort_t* dst; int N; int K; int Kpad; int rowofs; int Nw; };
struct PJobs { PJob j[20]; };

__global__ __launch_bounds__(256) void k_prep(PJobs P){
  const int job = blockIdx.x >> 2;
  const int sub = blockIdx.x & 3;
  PJob pj = P.j[job];
  const int elems = pj.Nw * pj.Kpad;
  for (int idx = sub*256 + threadIdx.x; idx < elems; idx += 4*256){
    int n = idx / pj.Kpad;
    int k = idx - n*pj.Kpad;
    float v = (n < pj.N && k < pj.K) ? pj.src[(size_t)n*pj.K + k] : 0.f;
    pj.dst[(size_t)(pj.rowofs + n)*pj.Kpad + k] = f2bf(v);
  }
}

// ---------------- k_enc1: e1(bf16) = silu(LN(obs @ w1.T + b1)) ----------------
__global__ __launch_bounds__(256) void k_enc1(
    const float* __restrict__ obs, const ushort_t* __restrict__ w1b,
    const float* __restrict__ b1, const float* __restrict__ g1,
    const float* __restrict__ bb1, ushort_t* __restrict__ e1)
{
  __shared__ __align__(16) char sm[34048];
  float*    s_val = (float*)sm;          // 32x264 f32
  ushort_t* s_a   = (ushort_t*)sm;       // 32x136 bf16 (aliases; dead after af load)
  float*    s_mr  = (float*)(sm + 33792);
  const int tok0 = blockIdx.x * 32;
  const int tid = threadIdx.x;
  const int lane = tid & 63, w = tid >> 6;
  const int q = lane >> 4, cn = lane & 15;
  const int m0 = (w & 1) * 16, nh = w >> 1;

  for (int e = tid; e < 32*16; e += 256){
    int t = e >> 4, kc = e & 15;
    const float* op = obs + (size_t)(tok0 + t)*OBSD;
    short8 v;
    #pragma unroll
    for (int j = 0; j < 8; j++){
      int k = kc*8 + j;
      v[j] = (short)f2bf(k < OBSD ? op[k] : 0.f);
    }
    *(short8*)&s_a[t*136 + kc*8] = v;
  }
  __syncthreads();

  short8 af[4];
  #pragma unroll
  for (int ks = 0; ks < 4; ks++)
    af[ks] = *(const short8*)&s_a[(m0 + cn)*136 + ks*32 + q*8];
  __syncthreads();

  #pragma unroll
  for (int nt = 0; nt < 8; nt++){
    const int n0 = (nh*8 + nt) * 16;
    f32x4 acc = {0.f,0.f,0.f,0.f};
    #pragma unroll
    for (int ks = 0; ks < 4; ks++){
      short8 bf = *(const short8*)&w1b[(size_t)(n0 + cn)*128 + ks*32 + q*8];
      acc = MFMA(af[ks], bf, acc);
    }
    float bias = b1[n0 + cn];
    #pragma unroll
    for (int r = 0; r < 4; r++)
      s_val[(m0 + q*4 + r)*264 + n0 + cn] = acc[r] + bias;
  }
  __syncthreads();

  ln32<256,264>(s_val, s_mr, tid);
  __syncthreads();
  for (int e = tid; e < 32*256; e += 256){
    int t = e >> 8, c = e & 255;
    float v = (s_val[t*264 + c] - s_mr[t*2]) * s_mr[t*2+1] * g1[c] + bb1[c];
    e1[(size_t)(tok0 + t)*256 + c] = f2bf(silu_f(v));
  }
}

// ------- k_enc2p: enc2+proj+LN(l0)+wig/wdbc(l0)+phaseA(l0, 2 sub-segments) -------
__global__ __launch_bounds__(256) void k_enc2p(
    const ushort_t* __restrict__ e1, const ushort_t* __restrict__ w2b,
    const float* __restrict__ b2, const float* __restrict__ g2,
    const float* __restrict__ bb2,
    const float* __restrict__ emb, const int* __restrict__ pact,
    const ushort_t* __restrict__ pwb, const float* __restrict__ pb,
    const float* __restrict__ pg, const float* __restrict__ pbb,
    float* __restrict__ X,
    const float* __restrict__ lng, const float* __restrict__ lnb,
    const ushort_t* __restrict__ wigb, const ushort_t* __restrict__ wdbcb,
    const float* __restrict__ bdt,
    ushort_t* __restrict__ XINb, ushort_t* __restrict__ Zb,
    ushort_t* __restrict__ DTb, ushort_t* __restrict__ BTu, ushort_t* __restrict__ CTu,
    const float* __restrict__ alog0,
    float* __restrict__ HLOC, float* __restrict__ PPR)
{
  __shared__ __align__(16) char sm[28928];
  float*    s_val = (float*)sm;                 // 32x136 f32
  ushort_t* s_xin = (ushort_t*)sm;              // aliases s_val after dead
  ushort_t* s_dt  = (ushort_t*)(sm + 8704);
  ushort_t* s_a   = (ushort_t*)(sm + 17408);    // 32x168 bf16
  ushort_t* s_btc = (ushort_t*)(sm + 28160);    // 32x8
  float*    s_mr  = (float*)(sm + 28672);

  const int tok0 = blockIdx.x * 32;
  const int bidx = blockIdx.x >> 4;
  const int ch   = blockIdx.x & 15;
  const int tid = threadIdx.x;
  const int lane = tid & 63, w = tid >> 6;
  const int q = lane >> 4, cn = lane & 15;
  const int m0 = (w & 1) * 16, nh = w >> 1;

  for (int e = tid; e < 32*32; e += 256){
    int t = e >> 5, k = e & 31;
    float v = 0.f;
    if (k < EMBD){ int a = pact[tok0 + t]; v = emb[(size_t)a*EMBD + k]; }
    s_a[t*168 + 128 + k] = f2bf(v);
  }
  {
    short8 af[8];
    #pragma unroll
    for (int ks = 0; ks < 8; ks++)
      af[ks] = *(const short8*)&e1[(size_t)(tok0 + m0 + cn)*256 + ks*32 + q*8];
    #pragma unroll
    for (int nt = 0; nt < 4; nt++){
      const int n0 = (nh*4 + nt) * 16;
      f32x4 acc = {0.f,0.f,0.f,0.f};
      #pragma unroll
      for (int ks = 0; ks < 8; ks++){
        short8 bf = *(const short8*)&w2b[(size_t)(n0 + cn)*256 + ks*32 + q*8];
        acc = MFMA(af[ks], bf, acc);
      }
      float bias = b2[n0 + cn];
      #pragma unroll
      for (int r = 0; r < 4; r++)
        s_val[(m0 + q*4 + r)*136 + n0 + cn] = acc[r] + bias;
    }
  }
  __syncthreads();

  ln32<128,136>(s_val, s_mr, tid);
  __syncthreads();
  for (int e = tid; e < 32*128; e += 256){
    int t = e >> 7, c = e & 127;
    float v = (s_val[t*136 + c] - s_mr[t*2]) * s_mr[t*2+1] * g2[c] + bb2[c];
    s_a[t*168 + c] = f2bf(v);
  }
  __syncthreads();

  {
    short8 af2[5];
    #pragma unroll
    for (int ks = 0; ks < 5; ks++)
      af2[ks] = *(const short8*)&s_a[(m0 + cn)*168 + ks*32 + q*8];
    #pragma unroll
    for (int nt = 0; nt < 4; nt++){
      const int n0 = (nh*4 + nt) * 16;
      f32x4 acc = {0.f,0.f,0.f,0.f};
      #pragma unroll
      for (int ks = 0; ks < 5; ks++){
        short8 bf = *(const short8*)&pwb[(size_t)(n0 + cn)*160 + ks*32 + q*8];
        acc = MFMA(af2[ks], bf, acc);
      }
      float bias = pb[n0 + cn];
      #pragma unroll
      for (int r = 0; r < 4; r++)
        s_val[(m0 + q*4 + r)*136 + n0 + cn] = acc[r] + bias;
    }
  }
  __syncthreads();

  ln32<128,136>(s_val, s_mr, tid);
  __syncthreads();
  for (int e = tid; e < 32*128; e += 256){
    int t = e >> 7, c = e & 127;
    float v = (s_val[t*136 + c] - s_mr[t*2]) * s_mr[t*2+1] * pg[c] + pbb[c];
    v = silu_f(v);
    X[(size_t)tok0*128 + e] = v;
    s_val[t*136 + c] = v;
  }
  __syncthreads();

  ln32<128,136>(s_val, s_mr, tid);
  __syncthreads();
  for (int e = tid; e < 32*128; e += 256){
    int t = e >> 7, c = e & 127;
    float v = (s_val[t*136 + c] - s_mr[t*2]) * s_mr[t*2+1] * lng[c] + lnb[c];
    s_a[t*168 + c] = f2bf(v);
  }
  __syncthreads();   // s_val DEAD; s_xin/s_dt may be written

  // wig GEMM
  {
    short8 af[4];
    #pragma unroll
    for (int ks = 0; ks < 4; ks++)
      af[ks] = *(const short8*)&s_a[(m0 + cn)*168 + ks*32 + q*8];
    #pragma unroll
    for (int nt = 0; nt < 8; nt++){
      const int n0 = (nh*8 + nt) * 16;
      f32x4 acc = {0.f,0.f,0.f,0.f};
      #pragma unroll
      for (int ks = 0; ks < 4; ks++){
        short8 bf = *(const short8*)&wigb[(size_t)(n0 + cn)*128 + ks*32 + q*8];
        acc = MFMA(af[ks], bf, acc);
      }
      if (n0 < 128){
        #pragma unroll
        for (int r = 0; r < 4; r++){
          int tr = m0 + q*4 + r;
          ushort_t bb = f2bf(acc[r]);
          XINb[(size_t)(tok0 + tr)*128 + n0 + cn] = bb;
          s_xin[tr*136 + n0 + cn] = bb;
        }
      } else {
        #pragma unroll
        for (int r = 0; r < 4; r++){
          int tr = m0 + q*4 + r;
          Zb[(size_t)(tok0 + tr)*128 + (n0 - 128) + cn] = f2bf(acc[r]);
        }
      }
    }
  }
  __syncthreads();

  // wdbc GEMM (also fills s_dt / s_btc for phase A)
  {
    short8 af2[4];
    #pragma unroll
    for (int ks = 0; ks < 4; ks++)
      af2[ks] = *(const short8*)&s_xin[(m0 + cn)*136 + ks*32 + q*8];
    for (int nt = nh; nt < 9; nt += 2){
      const int n0 = nt * 16;
      f32x4 acc = {0.f,0.f,0.f,0.f};
      #pragma unroll
      for (int ks = 0; ks < 4; ks++){
        short8 bf = *(const short8*)&wdbcb[(size_t)(n0 + cn)*128 + ks*32 + q*8];
        acc = MFMA(af2[ks], bf, acc);
      }
      const int col = n0 + cn;
      if (col < 128){
        float bd = bdt[col];
        #pragma unroll
        for (int r = 0; r < 4; r++){
          int tr = m0 + q*4 + r;
          ushort_t dv = f2bf(softplus_f(acc[r] + bd));
          DTb[(size_t)(tok0 + tr)*128 + col] = dv;
          s_dt[tr*136 + col] = dv;
        }
      } else if (col < 136){
        #pragma unroll
        for (int r = 0; r < 4; r++){
          int tr = m0 + q*4 + r;
          ushort_t bb = f2bf(acc[r]);
          BTu[(size_t)(tok0 + tr)*8 + (col - 128)] = bb;
          s_btc[tr*8 + (col - 128)] = bb;
        }
      } else {
        #pragma unroll
        for (int r = 0; r < 4; r++)
          CTu[(size_t)(tok0 + m0 + q*4 + r)*8 + (col - 136)] = f2bf(acc[r]);
      }
    }
  }
  __syncthreads();

  // phase A (layer 0): two 16-token sub-segments; thread = (d, 4-s-group)
  {
    const int d = tid & 127, sh = tid >> 7;
    float A2c[4];
    #pragma unroll
    for (int j = 0; j < 4; j++)
      A2c[j] = -__expf(alog0[d*8 + sh*4 + j]) * LOG2E;
    #pragma unroll
    for (int half = 0; half < 2; half++){
      float hh[4] = {0.f,0.f,0.f,0.f}, pp[4] = {1.f,1.f,1.f,1.f};
      for (int t = half*16; t < half*16 + 16; t++){
        float dt = b2f(s_dt[t*136 + d]);
        float wv = dt * b2f(s_xin[t*136 + d]);
        #pragma unroll
        for (int j = 0; j < 4; j++){
          float dA = exp2f(dt * A2c[j]);
          hh[j] = fmaf(dA, hh[j], wv * b2f(s_btc[t*8 + sh*4 + j]));
          pp[j] *= dA;
        }
      }
      const size_t o = ((size_t)bidx*SSEG + ch*2 + half)*1024 + d*8 + sh*4;
      #pragma unroll
      for (int j = 0; j < 4; j++){ HLOC[o+j] = hh[j]; PPR[o+j] = pp[j]; }
    }
  }
}

// LDS layout for scan kernels (TSEG=16, bytes):
//  0     : s_dtS (4096) ; 4096: s_xiS (4096)   [staging]
//  8192  : s_a bf16 16x136 (4352)
//  12544 : s_bt (256) ; 12800: s_ct (256) ; 13056: s_mr (128)
//  s_x f32 16x130 (8320) aliases [0,8320): staging (dead) + s_a head (af preloaded)
//  s_xin bf16 16x136 (4352) aliases [0,4352)
#define SMS 13184

// ======== phase B (inline carry, z from global) + wout GEMM + X residual + LN stats ========
__device__ __forceinline__ void phaseB_post(
    const ushort_t* DTb, const ushort_t* XINb, const ushort_t* Zb,
    const ushort_t* BTu, const ushort_t* CTu,
    const float* __restrict__ alog, const float* __restrict__ h0g,
    const float* __restrict__ HLi, const float* __restrict__ PPi,
    const float* __restrict__ dpar, const ushort_t* __restrict__ woutb,
    float* __restrict__ X, char* sm, int b, int sg)
{
  ushort_t* s_dtS = (ushort_t*)sm;
  ushort_t* s_xiS = (ushort_t*)(sm + 4096);
  ushort_t* s_a   = (ushort_t*)(sm + 8192);
  float*    s_x   = (float*)sm;
  ushort_t* s_bt  = (ushort_t*)(sm + 12544);
  ushort_t* s_ct  = (ushort_t*)(sm + 12800);
  float*    s_mr  = (float*)(sm + 13056);

  const int tid = threadIdx.x;
  const int d = tid;
  const int w = tid >> 6, lane = tid & 63, q = lane >> 4, cn = lane & 15;
  const size_t segtok = (size_t)b*TT + sg*TSEG;

  // stage dt/xi (4 KB each, uint4 coalesced) + bt/ct
  {
    const uint4* gdt = (const uint4*)(DTb + segtok*128);
    const uint4* gxi = (const uint4*)(XINb + segtok*128);
    #pragma unroll
    for (int i = 0; i < 2; i++){
      ((uint4*)s_dtS)[tid + i*128] = gdt[tid + i*128];
      ((uint4*)s_xiS)[tid + i*128] = gxi[tid + i*128];
    }
    if (tid < 64){
      ((unsigned*)s_bt)[tid] = ((const unsigned*)(BTu + segtok*8))[tid];
      ((unsigned*)s_ct)[tid] = ((const unsigned*)(CTu + segtok*8))[tid];
    }
  }
  // inline carry: prefix over segments < sg
  float A2[8], h[8];
  #pragma unroll
  for (int s = 0; s < 8; s++){
    A2[s] = -__expf(alog[d*8 + s]) * LOG2E;
    h[s] = h0g[(size_t)b*1024 + d*8 + s];
  }
  for (int ch = 0; ch < sg; ch++){
    const size_t o = ((size_t)b*SSEG + ch)*1024 + d*8;
    float4 hl0 = *(const float4*)(HLi + o);
    float4 hl1 = *(const float4*)(HLi + o + 4);
    float4 pp0 = *(const float4*)(PPi + o);
    float4 pp1 = *(const float4*)(PPi + o + 4);
    h[0]=fmaf(pp0.x,h[0],hl0.x); h[1]=fmaf(pp0.y,h[1],hl0.y);
    h[2]=fmaf(pp0.z,h[2],hl0.z); h[3]=fmaf(pp0.w,h[3],hl0.w);
    h[4]=fmaf(pp1.x,h[4],hl1.x); h[5]=fmaf(pp1.y,h[5],hl1.y);
    h[6]=fmaf(pp1.z,h[6],hl1.z); h[7]=fmaf(pp1.w,h[7],hl1.w);
  }
  __syncthreads();

  // scan: y only
  #pragma unroll 4
  for (int t = 0; t < TSEG; t++){
    float dt = b2f(s_dtS[t*128 + d]);
    float xi = b2f(s_xiS[t*128 + d]);
    float wv = dt * xi;
    float y = 0.f;
    #pragma unroll
    for (int s = 0; s < 8; s++){
      float dA = exp2f(dt * A2[s]);
      h[s] = fmaf(dA, h[s], wv * b2f(s_bt[t*8 + s]));
      y = fmaf(h[s], b2f(s_ct[t*8 + s]), y);
    }
    s_a[t*136 + d] = f2bf(y);
  }
  __syncthreads();

  // z-apply: ssm = y*silu(z) + xi*dp  (z coalesced from global)
  {
    const int c0 = (tid & 15)*8, trow = tid >> 4;
    float dpv[8];
    #pragma unroll
    for (int j = 0; j < 8; j++) dpv[j] = dpar[c0 + j];
    #pragma unroll
    for (int i = 0; i < 2; i++){
      const int t = trow + i*8;
      uint4 zb = ((const uint4*)(Zb + segtok*128))[tid + i*128];
      const ushort_t* zp = (const ushort_t*)&zb;
      #pragma unroll
      for (int j = 0; j < 8; j++){
        float y  = b2f(s_a[t*136 + c0 + j]);
        float xi = b2f(s_xiS[t*128 + c0 + j]);
        float ssm = y * silu_f(b2f(zp[j])) + xi * dpv[j];
        s_a[t*136 + c0 + j] = f2bf(ssm);
      }
    }
  }
  __syncthreads();

  // wout GEMM (16x128 @ 128^T) + residual -> s_x + X
  {
    short8 af[4];
    #pragma unroll
    for (int ks = 0; ks < 4; ks++)
      af[ks] = *(const short8*)&s_a[cn*136 + ks*32 + q*8];
    __syncthreads();   // s_a consumed before s_x writes (s_x aliases s_a head)
    for (int nt = w; nt < 8; nt += 2){
      const int n0 = nt * 16;
      short8 bf[4];
      #pragma unroll
      for (int ks = 0; ks < 4; ks++)
        bf[ks] = *(const short8*)&woutb[(size_t)(n0+cn)*128 + ks*32 + q*8];
      f32x4 acc = {0.f,0.f,0.f,0.f};
      #pragma unroll
      for (int ks = 0; ks < 4; ks++) acc = MFMA(af[ks], bf[ks], acc);
      #pragma unroll
      for (int r = 0; r < 4; r++){
        const int tr = q*4 + r;
        const size_t g = (segtok + tr)*128 + n0 + cn;
        float xn = X[g] + acc[r];
        X[g] = xn;
        s_x[tr*130 + n0 + cn] = xn;
      }
    }
  }
  __syncthreads();

  // LN stats (8 thr/token)
  {
    const int t = tid >> 3, part = tid & 7;
    float s = 0.f, s2 = 0.f;
    #pragma unroll
    for (int j = part; j < 128; j += 8){ float v = s_x[t*130 + j]; s += v; s2 = fmaf(v, v, s2); }
    s += __shfl_xor(s, 1, 64); s2 += __shfl_xor(s2, 1, 64);
    s += __shfl_xor(s, 2, 64); s2 += __shfl_xor(s2, 2, 64);
    s += __shfl_xor(s, 4, 64); s2 += __shfl_xor(s2, 4, 64);
    if (part == 0){
      float m = s * (1.f/128.f);
      s_mr[t*2] = m;
      s_mr[t*2+1] = rsqrtf(s2*(1.f/128.f) - m*m + 1e-5f);
    }
  }
  __syncthreads();
}

// normalize helper: s_x(16x130) -> s_a bf16 (16x136); row 15 preloaded (s_a aliases s_x tail)
__device__ __forceinline__ void norm16(const float* s_x, const float* s_mr,
    ushort_t* s_a, const float* __restrict__ gv, const float* __restrict__ bv,
    int tid, bool dosilu)
{
  float g = gv[tid], c0 = bv[tid];
  float x15 = s_x[15*130 + tid];
  __syncthreads();
  for (int t = 0; t < 15; t++){
    float v = (s_x[t*130 + tid] - s_mr[t*2]) * s_mr[t*2+1] * g + c0;
    if (dosilu) v = silu_f(v);
    s_a[t*136 + tid] = f2bf(v);
  }
  float v = (x15 - s_mr[30]) * s_mr[31] * g + c0;
  if (dosilu) v = silu_f(v);
  s_a[15*136 + tid] = f2bf(v);
}

// ---- k_scan2p: phaseB(l)+post(l)+LN+pre(l+1)+phaseA(l+1); grid BB*SSEG, 128 thr ----
__global__ __launch_bounds__(128) void k_scan2p(
    ushort_t* DTb, ushort_t* XINb, ushort_t* Zb,
    ushort_t* BTu, ushort_t* CTu,
    const float* __restrict__ alog, const float* __restrict__ h0g,
    const float* __restrict__ HLi, const float* __restrict__ PPi,
    const float* __restrict__ dpar, const ushort_t* __restrict__ woutb,
    float* __restrict__ X,
    const float* __restrict__ lng, const float* __restrict__ lnb,
    const ushort_t* __restrict__ wigb, const ushort_t* __restrict__ wdbcb,
    const float* __restrict__ bdt,
    const float* __restrict__ alogn,
    float* __restrict__ HLo, float* __restrict__ PPo)
{
  __shared__ __align__(16) char sm[SMS];
  ushort_t* s_a  = (ushort_t*)(sm + 8192);
  float*    s_x  = (float*)sm;
  ushort_t* s_xin= (ushort_t*)sm;
  ushort_t* s_bt = (ushort_t*)(sm + 12544);
  float*    s_mr = (float*)(sm + 13056);

  const int b = blockIdx.x >> 5, sg = blockIdx.x & 31;
  const int tid = threadIdx.x;
  const int w = tid >> 6, lane = tid & 63, q = lane >> 4, cn = lane & 15;
  const size_t segtok = (size_t)b*TT + sg*TSEG;

  phaseB_post(DTb, XINb, Zb, BTu, CTu, alog, h0g, HLi, PPi, dpar, woutb, X, sm, b, sg);

  norm16(s_x, s_mr, s_a, lng, lnb, tid, false);
  __syncthreads();

  // wig GEMM (M=16)
  {
    short8 af[4];
    #pragma unroll
    for (int ks = 0; ks < 4; ks++)
      af[ks] = *(const short8*)&s_a[cn*136 + ks*32 + q*8];
    for (int nt = w; nt < 16; nt += 2){
      const int n0 = nt * 16;
      short8 bf[4];
      #pragma unroll
      for (int ks = 0; ks < 4; ks++)
        bf[ks] = *(const short8*)&wigb[(size_t)(n0+cn)*128 + ks*32 + q*8];
      f32x4 acc = {0.f,0.f,0.f,0.f};
      #pragma unroll
      for (int ks = 0; ks < 4; ks++) acc = MFMA(af[ks], bf[ks], acc);
      if (n0 < 128){
        #pragma unroll
        for (int r = 0; r < 4; r++){
          const int tr = q*4 + r;
          ushort_t bb = f2bf(acc[r]);
          XINb[(segtok + tr)*128 + n0 + cn] = bb;
          s_xin[tr*136 + n0 + cn] = bb;
        }
      } else {
        #pragma unroll
        for (int r = 0; r < 4; r++){
          const int tr = q*4 + r;
          Zb[(segtok + tr)*128 + (n0-128) + cn] = f2bf(acc[r]);
        }
      }
    }
  }
  __syncthreads();

  // wdbc GEMM (fills s_a=next-dt, s_bt=next-bt)
  {
    short8 af[4];
    #pragma unroll
    for (int ks = 0; ks < 4; ks++)
      af[ks] = *(const short8*)&s_xin[cn*136 + ks*32 + q*8];
    for (int nt = w; nt < 9; nt += 2){
      const int n0 = nt * 16;
      short8 bf[4];
      #pragma unroll
      for (int ks = 0; ks < 4; ks++)
        bf[ks] = *(const short8*)&wdbcb[(size_t)(n0+cn)*128 + ks*32 + q*8];
      const int col = n0 + cn;
      f32x4 acc = {0.f,0.f,0.f,0.f};
      #pragma unroll
      for (int ks = 0; ks < 4; ks++) acc = MFMA(af[ks], bf[ks], acc);
      if (col < 128){
        float bd = bdt[col];
        #pragma unroll
        for (int r = 0; r < 4; r++){
          const int tr = q*4 + r;
          ushort_t dv = f2bf(softplus_f(acc[r] + bd));
          DTb[(segtok + tr)*128 + col] = dv;
          s_a[tr*136 + col] = dv;
        }
      } else if (col < 136){
        #pragma unroll
        for (int r = 0; r < 4; r++){
          const int tr = q*4 + r;
          ushort_t bb = f2bf(acc[r]);
          BTu[(segtok + tr)*8 + (col-128)] = bb;
          s_bt[tr*8 + (col-128)] = bb;
        }
      } else {
        #pragma unroll
        for (int r = 0; r < 4; r++)
          CTu[(segtok + q*4 + r)*8 + (col-136)] = f2bf(acc[r]);
      }
    }
  }
  __syncthreads();

  // phase A (next layer) over this 16-token segment
  {
    float A2n[8], hh[8], pp[8];
    #pragma unroll
    for (int s = 0; s < 8; s++){
      A2n[s] = -__expf(alogn[tid*8 + s]) * LOG2E;
      hh[s] = 0.f; pp[s] = 1.f;
    }
    for (int t = 0; t < TSEG; t++){
      float dt = b2f(s_a[t*136 + tid]);
      float wv = dt * b2f(s_xin[t*136 + tid]);
      #pragma unroll
      for (int s = 0; s < 8; s++){
        float dA = exp2f(dt * A2n[s]);
        hh[s] = fmaf(dA, hh[s], wv * b2f(s_bt[t*8 + s]));
        pp[s] *= dA;
      }
    }
    const size_t o = ((size_t)b*SSEG + sg)*1024 + tid*8;
    #pragma unroll
    for (int s = 0; s < 8; s++){ HLo[o+s] = hh[s]; PPo[o+s] = pp[s]; }
  }
}

// ---- k_scan2h: phaseB(l2)+post(l2)+LNfn+head; grid BB*SSEG, 128 thr ----
__global__ __launch_bounds__(128) void k_scan2h(
    const ushort_t* DTb, const ushort_t* XINb, const ushort_t* Zb,
    const ushort_t* BTu, const ushort_t* CTu,
    const float* __restrict__ alog, const float* __restrict__ h0g,
    const float* __restrict__ HLi, const float* __restrict__ PPi,
    const float* __restrict__ dpar, const ushort_t* __restrict__ woutb,
    float* __restrict__ X,
    const float* __restrict__ fng, const float* __restrict__ fnb,
    const ushort_t* __restrict__ pw1b, const float* __restrict__ pb1,
    const float* __restrict__ pg, const float* __restrict__ pbb,
    const ushort_t* __restrict__ pw2b, const float* __restrict__ pb2,
    float* __restrict__ out)
{
  __shared__ __align__(16) char sm[SMS];
  ushort_t* s_a  = (ushort_t*)(sm + 8192);
  float*    s_x  = (float*)sm;
  float*    s_mr = (float*)(sm + 13056);

  const int b = blockIdx.x >> 5, sg = blockIdx.x & 31;
  const int tid = threadIdx.x;
  const int w = tid >> 6, lane = tid & 63, q = lane >> 4, cn = lane & 15;
  const size_t segtok = (size_t)b*TT + sg*TSEG;

  phaseB_post((ushort_t*)DTb, (ushort_t*)XINb, (ushort_t*)Zb,
              (ushort_t*)BTu, (ushort_t*)CTu, alog, h0g, HLi, PPi,
              dpar, woutb, X, sm, b, sg);

  norm16(s_x, s_mr, s_a, fng, fnb, tid, false);
  __syncthreads();

  // pw1 GEMM -> s_x (+bias); af loaded before s_x writes
  {
    short8 af[4];
    #pragma unroll
    for (int ks = 0; ks < 4; ks++)
      af[ks] = *(const short8*)&s_a[cn*136 + ks*32 + q*8];
    __syncthreads();
    for (int nt = w; nt < 8; nt += 2){
      const int n0 = nt * 16;
      short8 bf[4];
      #pragma unroll
      for (int ks = 0; ks < 4; ks++)
        bf[ks] = *(const short8*)&pw1b[(size_t)(n0+cn)*128 + ks*32 + q*8];
      float bias = pb1[n0 + cn];
      f32x4 acc = {0.f,0.f,0.f,0.f};
      #pragma unroll
      for (int ks = 0; ks < 4; ks++) acc = MFMA(af[ks], bf[ks], acc);
      #pragma unroll
      for (int r = 0; r < 4; r++)
        s_x[(q*4 + r)*130 + n0 + cn] = acc[r] + bias;
    }
  }
  __syncthreads();

  // LN stats (8 thr/token)
  {
    const int t = tid >> 3, part = tid & 7;
    float s = 0.f, s2 = 0.f;
    #pragma unroll
    for (int j = part; j < 128; j += 8){ float v = s_x[t*130 + j]; s += v; s2 = fmaf(v, v, s2); }
    s += __shfl_xor(s, 1, 64); s2 += __shfl_xor(s2, 1, 64);
    s += __shfl_xor(s, 2, 64); s2 += __shfl_xor(s2, 2, 64);
    s += __shfl_xor(s, 4, 64); s2 += __shfl_xor(s2, 4, 64);
    if (part == 0){
      float m = s * (1.f/128.f);
      s_mr[t*2] = m;
      s_mr[t*2+1] = rsqrtf(s2*(1.f/128.f) - m*m + 1e-5f);
    }
  }
  __syncthreads();
  norm16(s_x, s_mr, s_a, pg, pbb, tid, true);
  __syncthreads();

  // pw2 GEMM: wave w -> n-tile w (cols w*16..w*16+15)
  {
    short8 af[4];
    #pragma unroll
    for (int ks = 0; ks < 4; ks++)
      af[ks] = *(const short8*)&s_a[cn*136 + ks*32 + q*8];
    const int n0 = w * 16;
    short8 bf[4];
    #pragma unroll
    for (int ks = 0; ks < 4; ks++)
      bf[ks] = *(const short8*)&pw2b[(size_t)(n0+cn)*128 + ks*32 + q*8];
    const int col = n0 + cn;
    f32x4 acc = {0.f,0.f,0.f,0.f};
    #pragma unroll
    for (int ks = 0; ks < 4; ks++) acc = MFMA(af[ks], bf[ks], acc);
    if (col < NAD){
      float bias = pb2[col];
      #pragma unroll
      for (int r = 0; r < 4; r++)
        out[(segtok + q*4 + r)*NAD + col] = acc[r] + bias;
    }
  }
}

extern "C" void kernel_launch(void* const* d_in, const int* in_sizes, int n_in,
                              void* d_out, int out_size, void* d_ws, size_t ws_size,
                              hipStream_t stream) {
  const float* obs    = (const float*)d_in[0];
  const float* h0     = (const float*)d_in[1];
  const float* enc_w1 = (const float*)d_in[2];
  const float* enc_b1 = (const float*)d_in[3];
  const float* enc_g1 = (const float*)d_in[4];
  const float* enc_bb1= (const float*)d_in[5];
  const float* enc_w2 = (const float*)d_in[6];
  const float* enc_b2 = (const float*)d_in[7];
  const float* enc_g2 = (const float*)d_in[8];
  const float* enc_bb2= (const float*)d_in[9];
  const float* emb    = (const float*)d_in[10];
  const float* proj_w = (const float*)d_in[11];
  const float* proj_b = (const float*)d_in[12];
  const float* proj_g = (const float*)d_in[13];
  const float* proj_bb= (const float*)d_in[14];
  const float* m_ln_g = (const float*)d_in[15];
  const float* m_ln_b = (const float*)d_in[16];
  const float* m_w_ig = (const float*)d_in[17];
  const float* m_w_dt = (const float*)d_in[18];
  const float* m_b_dt = (const float*)d_in[19];
  const float* m_a_log= (const float*)d_in[20];
  const float* m_w_b  = (const float*)d_in[21];
  const float* m_w_c  = (const float*)d_in[22];
  const float* m_d    = (const float*)d_in[23];
  const float* m_w_out= (const float*)d_in[24];
  const float* fn_g   = (const float*)d_in[25];
  const float* fn_b   = (const float*)d_in[26];
  const float* pol_w1 = (const float*)d_in[27];
  const float* pol_b1 = (const float*)d_in[28];
  const float* pol_g  = (const float*)d_in[29];
  const float* pol_bb = (const float*)d_in[30];
  const float* pol_w2 = (const float*)d_in[31];
  const float* pol_b2 = (const float*)d_in[32];
  const int*   pact   = (const int*)d_in[33];

  float* ws  = (float*)d_ws;
  float* X    = ws;
  float* HLA  = X + (size_t)NTOK*128;
  float* PPA  = HLA + (size_t)BB*SSEG*1024;
  float* HLB  = PPA + (size_t)BB*SSEG*1024;
  float* PPB  = HLB + (size_t)BB*SSEG*1024;
  ushort_t* E1   = (ushort_t*)(PPB + (size_t)BB*SSEG*1024);
  ushort_t* XINb = E1   + (size_t)NTOK*256;
  ushort_t* Zb   = XINb + (size_t)NTOK*128;
  ushort_t* DTb  = Zb   + (size_t)NTOK*128;
  ushort_t* BTu  = DTb  + (size_t)NTOK*128;
  ushort_t* CTu  = BTu  + (size_t)NTOK*8;

  ushort_t* W1B   = CTu   + (size_t)NTOK*8;
  ushort_t* W2B   = W1B   + 256*128;
  ushort_t* PWB   = W2B   + 128*256;
  ushort_t* WIGB  = PWB   + 128*160;
  ushort_t* WDBCB = WIGB  + 3*256*128;
  ushort_t* WOUTB = WDBCB + 3*144*128;
  ushort_t* PW1B  = WOUTB + 3*128*128;
  ushort_t* PW2B  = PW1B  + 128*128;

  PJobs P;
  int nj = 0;
  auto add = [&](const float* src, ushort_t* dst, int N, int K, int Kpad, int rowofs, int Nw){
    P.j[nj].src = src; P.j[nj].dst = dst; P.j[nj].N = N; P.j[nj].K = K;
    P.j[nj].Kpad = Kpad; P.j[nj].rowofs = rowofs; P.j[nj].Nw = Nw; nj++;
  };
  add(enc_w1, W1B, 256, 115, 128, 0, 256);
  add(enc_w2, W2B, 128, 256, 256, 0, 128);
  add(proj_w, PWB, 128, 144, 160, 0, 128);
  for (int l = 0; l < NLD; l++)
    add(m_w_ig + (size_t)l*256*128, WIGB + (size_t)l*256*128, 256, 128, 128, 0, 256);
  for (int l = 0; l < NLD; l++){
    add(m_w_dt + (size_t)l*128*128, WDBCB + (size_t)l*144*128, 128, 128, 128, 0,   128);
    add(m_w_b  + (size_t)l*8*128,   WDBCB + (size_t)l*144*128,   8, 128, 128, 128,   8);
    add(m_w_c  + (size_t)l*8*128,   WDBCB + (size_t)l*144*128,   8, 128, 128, 136,   8);
  }
  for (int l = 0; l < NLD; l++)
    add(m_w_out + (size_t)l*128*128, WOUTB + (size_t)l*128*128, 128, 128, 128, 0, 128);
  add(pol_w1, PW1B, 128, 128, 128, 0, 128);
  add(pol_w2, PW2B,  19, 128, 128, 0,  32);

  k_prep<<<20*4, 256, 0, stream>>>(P);
  k_enc1<<<NTOK/32, 256, 0, stream>>>(obs, W1B, enc_b1, enc_g1, enc_bb1, E1);
  k_enc2p<<<NTOK/32, 256, 0, stream>>>(E1, W2B, enc_b2, enc_g2, enc_bb2,
      emb, pact, PWB, proj_b, proj_g, proj_bb, X,
      m_ln_g, m_ln_b, WIGB, WDBCB, m_b_dt,
      XINb, Zb, DTb, BTu, CTu,
      m_a_log, HLA, PPA);

  // layer 0: reads A, writes B
  k_scan2p<<<BB*SSEG, 128, 0, stream>>>(DTb, XINb, Zb, BTu, CTu,
      m_a_log, h0, HLA, PPA, m_d, WOUTB, X,
      m_ln_g + 128, m_ln_b + 128,
      WIGB + (size_t)256*128, WDBCB + (size_t)144*128, m_b_dt + 128,
      m_a_log + 1024, HLB, PPB);
  // layer 1: reads B, writes A
  k_scan2p<<<BB*SSEG, 128, 0, stream>>>(DTb, XINb, Zb, BTu, CTu,
      m_a_log + 1024, h0 + (size_t)BB*1024, HLB, PPB, m_d + 128,
      WOUTB + (size_t)128*128, X,
      m_ln_g + 256, m_ln_b + 256,
      WIGB + (size_t)2*256*128, WDBCB + (size_t)2*144*128, m_b_dt + 256,
      m_a_log + 2048, HLA, PPA);
  // layer 2: reads A
  k_scan2h<<<BB*SSEG, 128, 0, stream>>>(DTb, XINb, Zb, BTu, CTu,
      m_a_log + 2048, h0 + (size_t)2*BB*1024, HLA, PPA, m_d + 256,
      WOUTB + (size_t)2*128*128, X,
      fn_g, fn_b, PW1B, pol_b1, pol_g, pol_bb, PW2B, pol_b2,
      (float*)d_out);
}

// Round 16
// 399.848 us; speedup vs baseline: 1.1677x; 1.1677x over previous
//
#include <hip/hip_runtime.h>
#include <math.h>

#define BB 64
#define TT 512
#define OBSD 115
#define DMD 128
#define DSD 8
#define NLD 3
#define EMBD 16
#define NAD 19
#define H1D 256
#define NTOK (BB*TT)
#define SSEG 16
#define TSEG (TT/SSEG)   // 32

typedef unsigned short ushort_t;
typedef __attribute__((ext_vector_type(8))) short short8;
typedef __attribute__((ext_vector_type(4))) float f32x4;

__device__ __forceinline__ float silu_f(float x){ return x / (1.f + __expf(-x)); }
__device__ __forceinline__ float softplus_f(float x){
  return fmaxf(x, 0.f) + log1pf(__expf(-fabsf(x)));
}
__device__ __forceinline__ ushort_t f2bf(float x){
  unsigned u = __float_as_uint(x);
  unsigned r = (u + 0x7fffu + ((u >> 16) & 1u)) >> 16;
  return (ushort_t)r;
}
__device__ __forceinline__ float b2f(ushort_t x){
  return __uint_as_float(((unsigned)x) << 16);
}
#define MFMA(a,b,c) __builtin_amdgcn_mfma_f32_16x16x32_bf16((a),(b),(c),0,0,0)
#define LOG2E 1.44269504f

// LN stats over 32 tokens, D cols, stride SV floats (SV%32==8 -> conflict-free).
template<int D, int SV>
__device__ __forceinline__ void ln32(const float* s_val, float* s_mr, int tid){
  const int t = tid >> 3, part = tid & 7;
  float s = 0.f, s2 = 0.f;
  #pragma unroll
  for (int j = part; j < D; j += 8){ float v = s_val[t*SV + j]; s += v; s2 = fmaf(v, v, s2); }
  s += __shfl_xor(s, 1, 64); s2 += __shfl_xor(s2, 1, 64);
  s += __shfl_xor(s, 2, 64); s2 += __shfl_xor(s2, 2, 64);
  s += __shfl_xor(s, 4, 64); s2 += __shfl_xor(s2, 4, 64);
  if (part == 0){
    float m = s * (1.f/(float)D);
    s_mr[t*2] = m;
    s_mr[t*2+1] = rsqrtf(s2 * (1.f/(float)D) - m*m + 1e-5f);
  }
}

// ---------------- k_prep ----------------
struct PJob { const float* src; ushort_t* dst; int N; int K; int Kpad; int rowofs; int Nw; };
struct PJobs { PJob j[20]; };

__global__ __launch_bounds__(256) void k_prep(PJobs P){
  const int job = blockIdx.x >> 2;
  const int sub = blockIdx.x & 3;
  PJob pj = P.j[job];
  const int elems = pj.Nw * pj.Kpad;
  for (int idx = sub*256 + threadIdx.x; idx < elems; idx += 4*256){
    int n = idx / pj.Kpad;
    int k = idx - n*pj.Kpad;
    float v = (n < pj.N && k < pj.K) ? pj.src[(size_t)n*pj.K + k] : 0.f;
    pj.dst[(size_t)(pj.rowofs + n)*pj.Kpad + k] = f2bf(v);
  }
}

// ---------------- k_enc1: e1(bf16) = silu(LN(obs @ w1.T + b1)) ----------------
__global__ __launch_bounds__(256) void k_enc1(
    const float* __restrict__ obs, const ushort_t* __restrict__ w1b,
    const float* __restrict__ b1, const float* __restrict__ g1,
    const float* __restrict__ bb1, ushort_t* __restrict__ e1)
{
  __shared__ __align__(16) char sm[34048];
  float*    s_val = (float*)sm;          // 32x264 f32
  ushort_t* s_a   = (ushort_t*)sm;       // 32x136 bf16 (aliases; dead after af load)
  float*    s_mr  = (float*)(sm + 33792);
  const int tok0 = blockIdx.x * 32;
  const int tid = threadIdx.x;
  const int lane = tid & 63, w = tid >> 6;
  const int q = lane >> 4, cn = lane & 15;
  const int m0 = (w & 1) * 16, nh = w >> 1;

  for (int e = tid; e < 32*16; e += 256){
    int t = e >> 4, kc = e & 15;
    const float* op = obs + (size_t)(tok0 + t)*OBSD;
    short8 v;
    #pragma unroll
    for (int j = 0; j < 8; j++){
      int k = kc*8 + j;
      v[j] = (short)f2bf(k < OBSD ? op[k] : 0.f);
    }
    *(short8*)&s_a[t*136 + kc*8] = v;
  }
  __syncthreads();

  short8 af[4];
  #pragma unroll
  for (int ks = 0; ks < 4; ks++)
    af[ks] = *(const short8*)&s_a[(m0 + cn)*136 + ks*32 + q*8];
  __syncthreads();

  #pragma unroll
  for (int nt = 0; nt < 8; nt++){
    const int n0 = (nh*8 + nt) * 16;
    f32x4 acc = {0.f,0.f,0.f,0.f};
    #pragma unroll
    for (int ks = 0; ks < 4; ks++){
      short8 bf = *(const short8*)&w1b[(size_t)(n0 + cn)*128 + ks*32 + q*8];
      acc = MFMA(af[ks], bf, acc);
    }
    float bias = b1[n0 + cn];
    #pragma unroll
    for (int r = 0; r < 4; r++)
      s_val[(m0 + q*4 + r)*264 + n0 + cn] = acc[r] + bias;
  }
  __syncthreads();

  ln32<256,264>(s_val, s_mr, tid);
  __syncthreads();
  for (int e = tid; e < 32*256; e += 256){
    int t = e >> 8, c = e & 255;
    float v = (s_val[t*264 + c] - s_mr[t*2]) * s_mr[t*2+1] * g1[c] + bb1[c];
    e1[(size_t)(tok0 + t)*256 + c] = f2bf(silu_f(v));
  }
}

// ------- k_enc2p: enc2+proj+LN(l0)+wig/wdbc(l0)+phaseA(l0) — 32 tok (=1 segment) -------
__global__ __launch_bounds__(256) void k_enc2p(
    const ushort_t* __restrict__ e1, const ushort_t* __restrict__ w2b,
    const float* __restrict__ b2, const float* __restrict__ g2,
    const float* __restrict__ bb2,
    const float* __restrict__ emb, const int* __restrict__ pact,
    const ushort_t* __restrict__ pwb, const float* __restrict__ pb,
    const float* __restrict__ pg, const float* __restrict__ pbb,
    float* __restrict__ X,
    const float* __restrict__ lng, const float* __restrict__ lnb,
    const ushort_t* __restrict__ wigb, const ushort_t* __restrict__ wdbcb,
    const float* __restrict__ bdt,
    ushort_t* __restrict__ XINb, ushort_t* __restrict__ Zb,
    ushort_t* __restrict__ DTb, ushort_t* __restrict__ BTu, ushort_t* __restrict__ CTu,
    const float* __restrict__ alog0,
    float* __restrict__ HLOC, float* __restrict__ PPR)
{
  __shared__ __align__(16) char sm[28928];
  float*    s_val = (float*)sm;                 // 32x136 f32
  ushort_t* s_xin = (ushort_t*)sm;              // aliases s_val after dead
  ushort_t* s_dt  = (ushort_t*)(sm + 8704);     // aliases s_val tail
  ushort_t* s_a   = (ushort_t*)(sm + 17408);    // 32x168 bf16
  ushort_t* s_btc = (ushort_t*)(sm + 28160);    // 32x8
  float*    s_mr  = (float*)(sm + 28672);

  const int tok0 = blockIdx.x * 32;
  const int bidx = blockIdx.x >> 4;
  const int ch   = blockIdx.x & 15;
  const int tid = threadIdx.x;
  const int lane = tid & 63, w = tid >> 6;
  const int q = lane >> 4, cn = lane & 15;
  const int m0 = (w & 1) * 16, nh = w >> 1;

  for (int e = tid; e < 32*32; e += 256){
    int t = e >> 5, k = e & 31;
    float v = 0.f;
    if (k < EMBD){ int a = pact[tok0 + t]; v = emb[(size_t)a*EMBD + k]; }
    s_a[t*168 + 128 + k] = f2bf(v);
  }
  {
    short8 af[8];
    #pragma unroll
    for (int ks = 0; ks < 8; ks++)
      af[ks] = *(const short8*)&e1[(size_t)(tok0 + m0 + cn)*256 + ks*32 + q*8];
    #pragma unroll
    for (int nt = 0; nt < 4; nt++){
      const int n0 = (nh*4 + nt) * 16;
      f32x4 acc = {0.f,0.f,0.f,0.f};
      #pragma unroll
      for (int ks = 0; ks < 8; ks++){
        short8 bf = *(const short8*)&w2b[(size_t)(n0 + cn)*256 + ks*32 + q*8];
        acc = MFMA(af[ks], bf, acc);
      }
      float bias = b2[n0 + cn];
      #pragma unroll
      for (int r = 0; r < 4; r++)
        s_val[(m0 + q*4 + r)*136 + n0 + cn] = acc[r] + bias;
    }
  }
  __syncthreads();

  ln32<128,136>(s_val, s_mr, tid);
  __syncthreads();
  for (int e = tid; e < 32*128; e += 256){
    int t = e >> 7, c = e & 127;
    float v = (s_val[t*136 + c] - s_mr[t*2]) * s_mr[t*2+1] * g2[c] + bb2[c];
    s_a[t*168 + c] = f2bf(v);
  }
  __syncthreads();

  {
    short8 af2[5];
    #pragma unroll
    for (int ks = 0; ks < 5; ks++)
      af2[ks] = *(const short8*)&s_a[(m0 + cn)*168 + ks*32 + q*8];
    #pragma unroll
    for (int nt = 0; nt < 4; nt++){
      const int n0 = (nh*4 + nt) * 16;
      f32x4 acc = {0.f,0.f,0.f,0.f};
      #pragma unroll
      for (int ks = 0; ks < 5; ks++){
        short8 bf = *(const short8*)&pwb[(size_t)(n0 + cn)*160 + ks*32 + q*8];
        acc = MFMA(af2[ks], bf, acc);
      }
      float bias = pb[n0 + cn];
      #pragma unroll
      for (int r = 0; r < 4; r++)
        s_val[(m0 + q*4 + r)*136 + n0 + cn] = acc[r] + bias;
    }
  }
  __syncthreads();

  ln32<128,136>(s_val, s_mr, tid);
  __syncthreads();
  for (int e = tid; e < 32*128; e += 256){
    int t = e >> 7, c = e & 127;
    float v = (s_val[t*136 + c] - s_mr[t*2]) * s_mr[t*2+1] * pg[c] + pbb[c];
    v = silu_f(v);
    X[(size_t)tok0*128 + e] = v;
    s_val[t*136 + c] = v;
  }
  __syncthreads();

  ln32<128,136>(s_val, s_mr, tid);
  __syncthreads();
  for (int e = tid; e < 32*128; e += 256){
    int t = e >> 7, c = e & 127;
    float v = (s_val[t*136 + c] - s_mr[t*2]) * s_mr[t*2+1] * lng[c] + lnb[c];
    s_a[t*168 + c] = f2bf(v);
  }
  __syncthreads();   // s_val DEAD; s_xin/s_dt may be written

  // wig GEMM
  {
    short8 af[4];
    #pragma unroll
    for (int ks = 0; ks < 4; ks++)
      af[ks] = *(const short8*)&s_a[(m0 + cn)*168 + ks*32 + q*8];
    #pragma unroll
    for (int nt = 0; nt < 8; nt++){
      const int n0 = (nh*8 + nt) * 16;
      f32x4 acc = {0.f,0.f,0.f,0.f};
      #pragma unroll
      for (int ks = 0; ks < 4; ks++){
        short8 bf = *(const short8*)&wigb[(size_t)(n0 + cn)*128 + ks*32 + q*8];
        acc = MFMA(af[ks], bf, acc);
      }
      if (n0 < 128){
        #pragma unroll
        for (int r = 0; r < 4; r++){
          int tr = m0 + q*4 + r;
          ushort_t bb = f2bf(acc[r]);
          XINb[(size_t)(tok0 + tr)*128 + n0 + cn] = bb;
          s_xin[tr*136 + n0 + cn] = bb;
        }
      } else {
        #pragma unroll
        for (int r = 0; r < 4; r++){
          int tr = m0 + q*4 + r;
          Zb[(size_t)(tok0 + tr)*128 + (n0 - 128) + cn] = f2bf(acc[r]);
        }
      }
    }
  }
  __syncthreads();

  // wdbc GEMM (also fills s_dt / s_btc for phase A)
  {
    short8 af2[4];
    #pragma unroll
    for (int ks = 0; ks < 4; ks++)
      af2[ks] = *(const short8*)&s_xin[(m0 + cn)*136 + ks*32 + q*8];
    for (int nt = nh; nt < 9; nt += 2){
      const int n0 = nt * 16;
      f32x4 acc = {0.f,0.f,0.f,0.f};
      #pragma unroll
      for (int ks = 0; ks < 4; ks++){
        short8 bf = *(const short8*)&wdbcb[(size_t)(n0 + cn)*128 + ks*32 + q*8];
        acc = MFMA(af2[ks], bf, acc);
      }
      const int col = n0 + cn;
      if (col < 128){
        float bd = bdt[col];
        #pragma unroll
        for (int r = 0; r < 4; r++){
          int tr = m0 + q*4 + r;
          ushort_t dv = f2bf(softplus_f(acc[r] + bd));
          DTb[(size_t)(tok0 + tr)*128 + col] = dv;
          s_dt[tr*136 + col] = dv;
        }
      } else if (col < 136){
        #pragma unroll
        for (int r = 0; r < 4; r++){
          int tr = m0 + q*4 + r;
          ushort_t bb = f2bf(acc[r]);
          BTu[(size_t)(tok0 + tr)*8 + (col - 128)] = bb;
          s_btc[tr*8 + (col - 128)] = bb;
        }
      } else {
        #pragma unroll
        for (int r = 0; r < 4; r++)
          CTu[(size_t)(tok0 + m0 + q*4 + r)*8 + (col - 136)] = f2bf(acc[r]);
      }
    }
  }
  __syncthreads();

  // phase A (layer 0): thread = (d, 4-s-group)
  {
    const int d = tid & 127, sh = tid >> 7;
    float A2c[4], hh[4], pp[4];
    #pragma unroll
    for (int j = 0; j < 4; j++){
      A2c[j] = -__expf(alog0[d*8 + sh*4 + j]) * LOG2E;
      hh[j] = 0.f; pp[j] = 1.f;
    }
    for (int t = 0; t < 32; t++){
      float dt = b2f(s_dt[t*136 + d]);
      float wv = dt * b2f(s_xin[t*136 + d]);
      #pragma unroll
      for (int j = 0; j < 4; j++){
        float dA = exp2f(dt * A2c[j]);
        hh[j] = fmaf(dA, hh[j], wv * b2f(s_btc[t*8 + sh*4 + j]));
        pp[j] *= dA;
      }
    }
    const size_t o = ((size_t)bidx*16 + ch)*1024 + d*8 + sh*4;
    #pragma unroll
    for (int j = 0; j < 4; j++){ HLOC[o+j] = hh[j]; PPR[o+j] = pp[j]; }
  }
}

// LDS layout per segment-slice (bytes):
//  0      : s_dtS (8192) ; 8192: s_xiS (8192)      [staging]
//  16384  : s_a bf16 32x136 (8704)
//  25088  : s_bt (512) ; 25600: s_ct (512) ; 26112: s_mr (256)
//  s_x f32 32x130 (16640) aliases [0,16640)
#define SMS 26368

// ======== phase B (inline carry, z from global) + wout GEMM + X residual + LN stats ========
// Runs on a 128-thread half-block with its own sm slice.
__device__ __forceinline__ void phaseB_post(
    const ushort_t* DTb, const ushort_t* XINb, const ushort_t* Zb,
    const ushort_t* BTu, const ushort_t* CTu,
    const float* __restrict__ alog, const float* __restrict__ h0g,
    const float* __restrict__ HLi, const float* __restrict__ PPi,
    const float* __restrict__ dpar, const ushort_t* __restrict__ woutb,
    float* __restrict__ X, char* sm, int b, int sg, int tid)
{
  ushort_t* s_dtS = (ushort_t*)sm;
  ushort_t* s_xiS = (ushort_t*)(sm + 8192);
  ushort_t* s_a   = (ushort_t*)(sm + 16384);
  float*    s_x   = (float*)sm;
  ushort_t* s_bt  = (ushort_t*)(sm + 25088);
  ushort_t* s_ct  = (ushort_t*)(sm + 25600);
  float*    s_mr  = (float*)(sm + 26112);

  const int d = tid;
  const int w = tid >> 6, lane = tid & 63, q = lane >> 4, cn = lane & 15;
  const size_t segtok = (size_t)b*TT + sg*TSEG;

  {
    const uint4* gdt = (const uint4*)(DTb + segtok*128);
    const uint4* gxi = (const uint4*)(XINb + segtok*128);
    #pragma unroll
    for (int i = 0; i < 4; i++){
      ((uint4*)s_dtS)[tid + i*128] = gdt[tid + i*128];
      ((uint4*)s_xiS)[tid + i*128] = gxi[tid + i*128];
    }
    ((unsigned*)s_bt)[tid] = ((const unsigned*)(BTu + segtok*8))[tid];
    ((unsigned*)s_ct)[tid] = ((const unsigned*)(CTu + segtok*8))[tid];
  }
  float A2[8], h[8];
  #pragma unroll
  for (int s = 0; s < 8; s++){
    A2[s] = -__expf(alog[d*8 + s]) * LOG2E;
    h[s] = h0g[(size_t)b*1024 + d*8 + s];
  }
  for (int ch = 0; ch < sg; ch++){
    const size_t o = ((size_t)b*SSEG + ch)*1024 + d*8;
    float4 hl0 = *(const float4*)(HLi + o);
    float4 hl1 = *(const float4*)(HLi + o + 4);
    float4 pp0 = *(const float4*)(PPi + o);
    float4 pp1 = *(const float4*)(PPi + o + 4);
    h[0]=fmaf(pp0.x,h[0],hl0.x); h[1]=fmaf(pp0.y,h[1],hl0.y);
    h[2]=fmaf(pp0.z,h[2],hl0.z); h[3]=fmaf(pp0.w,h[3],hl0.w);
    h[4]=fmaf(pp1.x,h[4],hl1.x); h[5]=fmaf(pp1.y,h[5],hl1.y);
    h[6]=fmaf(pp1.z,h[6],hl1.z); h[7]=fmaf(pp1.w,h[7],hl1.w);
  }
  __syncthreads();

  // scan: y only
  #pragma unroll 4
  for (int t = 0; t < 32; t++){
    float dt = b2f(s_dtS[t*128 + d]);
    float xi = b2f(s_xiS[t*128 + d]);
    float wv = dt * xi;
    float y = 0.f;
    #pragma unroll
    for (int s = 0; s < 8; s++){
      float dA = exp2f(dt * A2[s]);
      h[s] = fmaf(dA, h[s], wv * b2f(s_bt[t*8 + s]));
      y = fmaf(h[s], b2f(s_ct[t*8 + s]), y);
    }
    s_a[t*136 + d] = f2bf(y);
  }
  __syncthreads();

  // z-apply: ssm = y*silu(z) + xi*dp
  {
    const int c0 = (tid & 15)*8, trow = tid >> 4;
    float dpv[8];
    #pragma unroll
    for (int j = 0; j < 8; j++) dpv[j] = dpar[c0 + j];
    #pragma unroll
    for (int i = 0; i < 4; i++){
      const int t = trow + i*8;
      uint4 zb = ((const uint4*)(Zb + segtok*128))[tid + i*128];
      const ushort_t* zp = (const ushort_t*)&zb;
      #pragma unroll
      for (int j = 0; j < 8; j++){
        float y  = b2f(s_a[t*136 + c0 + j]);
        float xi = b2f(s_xiS[t*128 + c0 + j]);
        float ssm = y * silu_f(b2f(zp[j])) + xi * dpv[j];
        s_a[t*136 + c0 + j] = f2bf(ssm);
      }
    }
  }
  __syncthreads();

  // wout GEMM (32x128 @ 128^T) + residual -> s_x + X
  {
    short8 af[2][4];
    #pragma unroll
    for (int mt = 0; mt < 2; mt++)
      #pragma unroll
      for (int ks = 0; ks < 4; ks++)
        af[mt][ks] = *(const short8*)&s_a[(mt*16 + cn)*136 + ks*32 + q*8];
    __syncthreads();   // s_a consumed before s_x writes
    for (int nt = w; nt < 8; nt += 2){
      const int n0 = nt * 16;
      short8 bf[4];
      #pragma unroll
      for (int ks = 0; ks < 4; ks++)
        bf[ks] = *(const short8*)&woutb[(size_t)(n0+cn)*128 + ks*32 + q*8];
      #pragma unroll
      for (int mt = 0; mt < 2; mt++){
        f32x4 acc = {0.f,0.f,0.f,0.f};
        #pragma unroll
        for (int ks = 0; ks < 4; ks++) acc = MFMA(af[mt][ks], bf[ks], acc);
        #pragma unroll
        for (int r = 0; r < 4; r++){
          const int tr = mt*16 + q*4 + r;
          const size_t g = (segtok + tr)*128 + n0 + cn;
          float xn = X[g] + acc[r];
          X[g] = xn;
          s_x[tr*130 + n0 + cn] = xn;
        }
      }
    }
  }
  __syncthreads();

  // LN stats (4 thr/token)
  {
    const int t = tid >> 2, qtr = tid & 3;
    float s = 0.f, s2 = 0.f;
    const float* row = s_x + t*130 + qtr*32;
    for (int j = 0; j < 32; j++){ float v = row[j]; s += v; s2 = fmaf(v, v, s2); }
    s  += __shfl_xor(s, 1, 64);  s2 += __shfl_xor(s2, 1, 64);
    s  += __shfl_xor(s, 2, 64);  s2 += __shfl_xor(s2, 2, 64);
    float m = s * (1.f/128.f);
    float var = s2 * (1.f/128.f) - m*m;
    if (qtr == 0){ s_mr[t*2] = m; s_mr[t*2+1] = rsqrtf(var + 1e-5f); }
  }
  __syncthreads();
}

// ---- k_scan2p: 256 thr = 2 independent segment slices; grid BB*SSEG/2 ----
__global__ __launch_bounds__(256) void k_scan2p(
    ushort_t* DTb, ushort_t* XINb, ushort_t* Zb,
    ushort_t* BTu, ushort_t* CTu,
    const float* __restrict__ alog, const float* __restrict__ h0g,
    const float* __restrict__ HLi, const float* __restrict__ PPi,
    const float* __restrict__ dpar, const ushort_t* __restrict__ woutb,
    float* __restrict__ X,
    const float* __restrict__ lng, const float* __restrict__ lnb,
    const ushort_t* __restrict__ wigb, const ushort_t* __restrict__ wdbcb,
    const float* __restrict__ bdt,
    const float* __restrict__ alogn,
    float* __restrict__ HLo, float* __restrict__ PPo)
{
  __shared__ __align__(16) char sm_all[2*SMS];
  const int sub = threadIdx.x >> 7;
  char* sm = sm_all + sub*SMS;
  const int tid = threadIdx.x & 127;

  ushort_t* s_a  = (ushort_t*)(sm + 16384);
  float*    s_x  = (float*)sm;
  ushort_t* s_xin= (ushort_t*)sm;
  ushort_t* s_bt = (ushort_t*)(sm + 25088);
  float*    s_mr = (float*)(sm + 26112);

  const int b = blockIdx.x >> 3;
  const int sg = (blockIdx.x & 7)*2 + sub;
  const int w = tid >> 6, lane = tid & 63, q = lane >> 4, cn = lane & 15;
  const size_t segtok = (size_t)b*TT + sg*TSEG;

  phaseB_post(DTb, XINb, Zb, BTu, CTu, alog, h0g, HLi, PPi, dpar, woutb, X, sm, b, sg, tid);

  // normalize -> s_a bf16 (row 31 preloaded: s_a head aliases s_x tail)
  {
    float g = lng[tid], c0 = lnb[tid];
    float x31 = s_x[31*130 + tid];
    __syncthreads();
    for (int t = 0; t < 31; t++){
      float v = (s_x[t*130 + tid] - s_mr[t*2]) * s_mr[t*2+1] * g + c0;
      s_a[t*136 + tid] = f2bf(v);
    }
    float v = (x31 - s_mr[62]) * s_mr[63] * g + c0;
    s_a[31*136 + tid] = f2bf(v);
  }
  __syncthreads();

  // wig GEMM
  {
    short8 af[2][4];
    #pragma unroll
    for (int mt = 0; mt < 2; mt++)
      #pragma unroll
      for (int ks = 0; ks < 4; ks++)
        af[mt][ks] = *(const short8*)&s_a[(mt*16 + cn)*136 + ks*32 + q*8];
    for (int nt = w; nt < 16; nt += 2){
      const int n0 = nt * 16;
      short8 bf[4];
      #pragma unroll
      for (int ks = 0; ks < 4; ks++)
        bf[ks] = *(const short8*)&wigb[(size_t)(n0+cn)*128 + ks*32 + q*8];
      #pragma unroll
      for (int mt = 0; mt < 2; mt++){
        f32x4 acc = {0.f,0.f,0.f,0.f};
        #pragma unroll
        for (int ks = 0; ks < 4; ks++) acc = MFMA(af[mt][ks], bf[ks], acc);
        if (n0 < 128){
          #pragma unroll
          for (int r = 0; r < 4; r++){
            const int tr = mt*16 + q*4 + r;
            ushort_t bb = f2bf(acc[r]);
            XINb[(segtok + tr)*128 + n0 + cn] = bb;
            s_xin[tr*136 + n0 + cn] = bb;
          }
        } else {
          #pragma unroll
          for (int r = 0; r < 4; r++){
            const int tr = mt*16 + q*4 + r;
            Zb[(segtok + tr)*128 + (n0-128) + cn] = f2bf(acc[r]);
          }
        }
      }
    }
  }
  __syncthreads();

  // wdbc GEMM (fills s_a=next-dt, s_bt=next-bt)
  {
    short8 af[2][4];
    #pragma unroll
    for (int mt = 0; mt < 2; mt++)
      #pragma unroll
      for (int ks = 0; ks < 4; ks++)
        af[mt][ks] = *(const short8*)&s_xin[(mt*16 + cn)*136 + ks*32 + q*8];
    for (int nt = w; nt < 9; nt += 2){
      const int n0 = nt * 16;
      short8 bf[4];
      #pragma unroll
      for (int ks = 0; ks < 4; ks++)
        bf[ks] = *(const short8*)&wdbcb[(size_t)(n0+cn)*128 + ks*32 + q*8];
      const int col = n0 + cn;
      #pragma unroll
      for (int mt = 0; mt < 2; mt++){
        f32x4 acc = {0.f,0.f,0.f,0.f};
        #pragma unroll
        for (int ks = 0; ks < 4; ks++) acc = MFMA(af[mt][ks], bf[ks], acc);
        if (col < 128){
          float bd = bdt[col];
          #pragma unroll
          for (int r = 0; r < 4; r++){
            const int tr = mt*16 + q*4 + r;
            ushort_t dv = f2bf(softplus_f(acc[r] + bd));
            DTb[(segtok + tr)*128 + col] = dv;
            s_a[tr*136 + col] = dv;
          }
        } else if (col < 136){
          #pragma unroll
          for (int r = 0; r < 4; r++){
            const int tr = mt*16 + q*4 + r;
            ushort_t bb = f2bf(acc[r]);
            BTu[(segtok + tr)*8 + (col-128)] = bb;
            s_bt[tr*8 + (col-128)] = bb;
          }
        } else {
          #pragma unroll
          for (int r = 0; r < 4; r++)
            CTu[(segtok + mt*16 + q*4 + r)*8 + (col-136)] = f2bf(acc[r]);
        }
      }
    }
  }
  __syncthreads();

  // phase A (next layer) over this segment
  {
    float A2n[8], hh[8], pp[8];
    #pragma unroll
    for (int s = 0; s < 8; s++){
      A2n[s] = -__expf(alogn[tid*8 + s]) * LOG2E;
      hh[s] = 0.f; pp[s] = 1.f;
    }
    for (int t = 0; t < 32; t++){
      float dt = b2f(s_a[t*136 + tid]);
      float wv = dt * b2f(s_xin[t*136 + tid]);
      #pragma unroll
      for (int s = 0; s < 8; s++){
        float dA = exp2f(dt * A2n[s]);
        hh[s] = fmaf(dA, hh[s], wv * b2f(s_bt[t*8 + s]));
        pp[s] *= dA;
      }
    }
    const size_t o = ((size_t)b*SSEG + sg)*1024 + tid*8;
    #pragma unroll
    for (int s = 0; s < 8; s++){ HLo[o+s] = hh[s]; PPo[o+s] = pp[s]; }
  }
}

// ---- k_scan2h: 256 thr = 2 segment slices; phaseB+post+LNfn+head ----
__global__ __launch_bounds__(256) void k_scan2h(
    const ushort_t* DTb, const ushort_t* XINb, const ushort_t* Zb,
    const ushort_t* BTu, const ushort_t* CTu,
    const float* __restrict__ alog, const float* __restrict__ h0g,
    const float* __restrict__ HLi, const float* __restrict__ PPi,
    const float* __restrict__ dpar, const ushort_t* __restrict__ woutb,
    float* __restrict__ X,
    const float* __restrict__ fng, const float* __restrict__ fnb,
    const ushort_t* __restrict__ pw1b, const float* __restrict__ pb1,
    const float* __restrict__ pg, const float* __restrict__ pbb,
    const ushort_t* __restrict__ pw2b, const float* __restrict__ pb2,
    float* __restrict__ out)
{
  __shared__ __align__(16) char sm_all[2*SMS];
  const int sub = threadIdx.x >> 7;
  char* sm = sm_all + sub*SMS;
  const int tid = threadIdx.x & 127;

  ushort_t* s_a  = (ushort_t*)(sm + 16384);
  float*    s_x  = (float*)sm;
  float*    s_mr = (float*)(sm + 26112);

  const int b = blockIdx.x >> 3;
  const int sg = (blockIdx.x & 7)*2 + sub;
  const int w = tid >> 6, lane = tid & 63, q = lane >> 4, cn = lane & 15;
  const size_t segtok = (size_t)b*TT + sg*TSEG;

  phaseB_post((ushort_t*)DTb, (ushort_t*)XINb, (ushort_t*)Zb,
              (ushort_t*)BTu, (ushort_t*)CTu, alog, h0g, HLi, PPi,
              dpar, woutb, X, sm, b, sg, tid);

  // LN_fn -> s_a bf16 (row 31 preloaded)
  {
    float g = fng[tid], c0 = fnb[tid];
    float x31 = s_x[31*130 + tid];
    __syncthreads();
    for (int t = 0; t < 31; t++){
      float v = (s_x[t*130 + tid] - s_mr[t*2]) * s_mr[t*2+1] * g + c0;
      s_a[t*136 + tid] = f2bf(v);
    }
    float v = (x31 - s_mr[62]) * s_mr[63] * g + c0;
    s_a[31*136 + tid] = f2bf(v);
  }
  __syncthreads();

  // pw1 GEMM -> s_x (+bias); af loaded before s_x writes
  {
    short8 af[2][4];
    #pragma unroll
    for (int mt = 0; mt < 2; mt++)
      #pragma unroll
      for (int ks = 0; ks < 4; ks++)
        af[mt][ks] = *(const short8*)&s_a[(mt*16 + cn)*136 + ks*32 + q*8];
    __syncthreads();
    for (int nt = w; nt < 8; nt += 2){
      const int n0 = nt * 16;
      short8 bf[4];
      #pragma unroll
      for (int ks = 0; ks < 4; ks++)
        bf[ks] = *(const short8*)&pw1b[(size_t)(n0+cn)*128 + ks*32 + q*8];
      float bias = pb1[n0 + cn];
      #pragma unroll
      for (int mt = 0; mt < 2; mt++){
        f32x4 acc = {0.f,0.f,0.f,0.f};
        #pragma unroll
        for (int ks = 0; ks < 4; ks++) acc = MFMA(af[mt][ks], bf[ks], acc);
        #pragma unroll
        for (int r = 0; r < 4; r++)
          s_x[(mt*16 + q*4 + r)*130 + n0 + cn] = acc[r] + bias;
      }
    }
  }
  __syncthreads();

  // LN stats (4 thr/token)
  {
    const int t = tid >> 2, qtr = tid & 3;
    float s = 0.f, s2 = 0.f;
    const float* row = s_x + t*130 + qtr*32;
    for (int j = 0; j < 32; j++){ float v = row[j]; s += v; s2 = fmaf(v, v, s2); }
    s  += __shfl_xor(s, 1, 64);  s2 += __shfl_xor(s2, 1, 64);
    s  += __shfl_xor(s, 2, 64);  s2 += __shfl_xor(s2, 2, 64);
    float m = s * (1.f/128.f);
    float var = s2 * (1.f/128.f) - m*m;
    if (qtr == 0){ s_mr[t*2] = m; s_mr[t*2+1] = rsqrtf(var + 1e-5f); }
  }
  __syncthreads();
  {
    float g = pg[tid], c0 = pbb[tid];
    float x31 = s_x[31*130 + tid];
    __syncthreads();
    for (int t = 0; t < 31; t++){
      float v = (s_x[t*130 + tid] - s_mr[t*2]) * s_mr[t*2+1] * g + c0;
      s_a[t*136 + tid] = f2bf(silu_f(v));
    }
    float v = (x31 - s_mr[62]) * s_mr[63] * g + c0;
    s_a[31*136 + tid] = f2bf(silu_f(v));
  }
  __syncthreads();

  // pw2 GEMM
  {
    short8 af[2][4];
    #pragma unroll
    for (int mt = 0; mt < 2; mt++)
      #pragma unroll
      for (int ks = 0; ks < 4; ks++)
        af[mt][ks] = *(const short8*)&s_a[(mt*16 + cn)*136 + ks*32 + q*8];
    const int n0 = w * 16;
    short8 bf[4];
    #pragma unroll
    for (int ks = 0; ks < 4; ks++)
      bf[ks] = *(const short8*)&pw2b[(size_t)(n0+cn)*128 + ks*32 + q*8];
    const int col = n0 + cn;
    #pragma unroll
    for (int mt = 0; mt < 2; mt++){
      f32x4 acc = {0.f,0.f,0.f,0.f};
      #pragma unroll
      for (int ks = 0; ks < 4; ks++) acc = MFMA(af[mt][ks], bf[ks], acc);
      if (col < NAD){
        float bias = pb2[col];
        #pragma unroll
        for (int r = 0; r < 4; r++)
          out[(segtok + mt*16 + q*4 + r)*NAD + col] = acc[r] + bias;
      }
    }
  }
}

extern "C" void kernel_launch(void* const* d_in, const int* in_sizes, int n_in,
                              void* d_out, int out_size, void* d_ws, size_t ws_size,
                              hipStream_t stream) {
  const float* obs    = (const float*)d_in[0];
  const float* h0     = (const float*)d_in[1];
  const float* enc_w1 = (const float*)d_in[2];
  const float* enc_b1 = (const float*)d_in[3];
  const float* enc_g1 = (const float*)d_in[4];
  const float* enc_bb1= (const float*)d_in[5];
  const float* enc_w2 = (const float*)d_in[6];
  const float* enc_b2 = (const float*)d_in[7];
  const float* enc_g2 = (const float*)d_in[8];
  const float* enc_bb2= (const float*)d_in[9];
  const float* emb    = (const float*)d_in[10];
  const float* proj_w = (const float*)d_in[11];
  const float* proj_b = (const float*)d_in[12];
  const float* proj_g = (const float*)d_in[13];
  const float* proj_bb= (const float*)d_in[14];
  const float* m_ln_g = (const float*)d_in[15];
  const float* m_ln_b = (const float*)d_in[16];
  const float* m_w_ig = (const float*)d_in[17];
  const float* m_w_dt = (const float*)d_in[18];
  const float* m_b_dt = (const float*)d_in[19];
  const float* m_a_log= (const float*)d_in[20];
  const float* m_w_b  = (const float*)d_in[21];
  const float* m_w_c  = (const float*)d_in[22];
  const float* m_d    = (const float*)d_in[23];
  const float* m_w_out= (const float*)d_in[24];
  const float* fn_g   = (const float*)d_in[25];
  const float* fn_b   = (const float*)d_in[26];
  const float* pol_w1 = (const float*)d_in[27];
  const float* pol_b1 = (const float*)d_in[28];
  const float* pol_g  = (const float*)d_in[29];
  const float* pol_bb = (const float*)d_in[30];
  const float* pol_w2 = (const float*)d_in[31];
  const float* pol_b2 = (const float*)d_in[32];
  const int*   pact   = (const int*)d_in[33];

  float* ws  = (float*)d_ws;
  float* X    = ws;
  float* HLA  = X + (size_t)NTOK*128;
  float* PPA  = HLA + (size_t)BB*SSEG*1024;
  float* HLB  = PPA + (size_t)BB*SSEG*1024;
  float* PPB  = HLB + (size_t)BB*SSEG*1024;
  ushort_t* E1   = (ushort_t*)(PPB + (size_t)BB*SSEG*1024);
  ushort_t* XINb = E1   + (size_t)NTOK*256;
  ushort_t* Zb   = XINb + (size_t)NTOK*128;
  ushort_t* DTb  = Zb   + (size_t)NTOK*128;
  ushort_t* BTu  = DTb  + (size_t)NTOK*128;
  ushort_t* CTu  = BTu  + (size_t)NTOK*8;

  ushort_t* W1B   = CTu   + (size_t)NTOK*8;
  ushort_t* W2B   = W1B   + 256*128;
  ushort_t* PWB   = W2B   + 128*256;
  ushort_t* WIGB  = PWB   + 128*160;
  ushort_t* WDBCB = WIGB  + 3*256*128;
  ushort_t* WOUTB = WDBCB + 3*144*128;
  ushort_t* PW1B  = WOUTB + 3*128*128;
  ushort_t* PW2B  = PW1B  + 128*128;

  PJobs P;
  int nj = 0;
  auto add = [&](const float* src, ushort_t* dst, int N, int K, int Kpad, int rowofs, int Nw){
    P.j[nj].src = src; P.j[nj].dst = dst; P.j[nj].N = N; P.j[nj].K = K;
    P.j[nj].Kpad = Kpad; P.j[nj].rowofs = rowofs; P.j[nj].Nw = Nw; nj++;
  };
  add(enc_w1, W1B, 256, 115, 128, 0, 256);
  add(enc_w2, W2B, 128, 256, 256, 0, 128);
  add(proj_w, PWB, 128, 144, 160, 0, 128);
  for (int l = 0; l < NLD; l++)
    add(m_w_ig + (size_t)l*256*128, WIGB + (size_t)l*256*128, 256, 128, 128, 0, 256);
  for (int l = 0; l < NLD; l++){
    add(m_w_dt + (size_t)l*128*128, WDBCB + (size_t)l*144*128, 128, 128, 128, 0,   128);
    add(m_w_b  + (size_t)l*8*128,   WDBCB + (size_t)l*144*128,   8, 128, 128, 128,   8);
    add(m_w_c  + (size_t)l*8*128,   WDBCB + (size_t)l*144*128,   8, 128, 128, 136,   8);
  }
  for (int l = 0; l < NLD; l++)
    add(m_w_out + (size_t)l*128*128, WOUTB + (size_t)l*128*128, 128, 128, 128, 0, 128);
  add(pol_w1, PW1B, 128, 128, 128, 0, 128);
  add(pol_w2, PW2B,  19, 128, 128, 0,  32);

  k_prep<<<20*4, 256, 0, stream>>>(P);
  k_enc1<<<NTOK/32, 256, 0, stream>>>(obs, W1B, enc_b1, enc_g1, enc_bb1, E1);
  k_enc2p<<<NTOK/32, 256, 0, stream>>>(E1, W2B, enc_b2, enc_g2, enc_bb2,
      emb, pact, PWB, proj_b, proj_g, proj_bb, X,
      m_ln_g, m_ln_b, WIGB, WDBCB, m_b_dt,
      XINb, Zb, DTb, BTu, CTu,
      m_a_log, HLA, PPA);

  const int scangrid = BB*SSEG/2;   // 512 blocks x 256 thr
  // layer 0: reads A, writes B
  k_scan2p<<<scangrid, 256, 0, stream>>>(DTb, XINb, Zb, BTu, CTu,
      m_a_log, h0, HLA, PPA, m_d, WOUTB, X,
      m_ln_g + 128, m_ln_b + 128,
      WIGB + (size_t)256*128, WDBCB + (size_t)144*128, m_b_dt + 128,
      m_a_log + 1024, HLB, PPB);
  // layer 1: reads B, writes A
  k_scan2p<<<scangrid, 256, 0, stream>>>(DTb, XINb, Zb, BTu, CTu,
      m_a_log + 1024, h0 + (size_t)BB*1024, HLB, PPB, m_d + 128,
      WOUTB + (size_t)128*128, X,
      m_ln_g + 256, m_ln_b + 256,
      WIGB + (size_t)2*256*128, WDBCB + (size_t)2*144*128, m_b_dt + 256,
      m_a_log + 2048, HLA, PPA);
  // layer 2: reads A
  k_scan2h<<<scangrid, 256, 0, stream>>>(DTb, XINb, Zb, BTu, CTu,
      m_a_log + 2048, h0 + (size_t)2*BB*1024, HLA, PPA, m_d + 256,
      WOUTB + (size_t)2*128*128, X,
      fn_g, fn_b, PW1B, pol_b1, pol_g, pol_bb, PW2B, pol_b2,
      (float*)d_out);
}